// Round 1
// baseline (1254.155 us; speedup 1.0000x reference)
//
#include <hip/hip_runtime.h>
#include <math.h>

#define EMBED 256
#define NF 3
#define DD 64
#define BM 128
#define BN 128
#define BK 32

// ---------------- Kernel 1: normalize + random_mapping -> x2, p, inv-norms ----
__global__ __launch_bounds__(64) void k_embed(
    const float* __restrict__ x,
    const float* __restrict__ feats,
    const float* __restrict__ feat_free,
    const float* __restrict__ ks,
    const float* __restrict__ Ws,
    const float* __restrict__ bias,
    const float* __restrict__ W_free,
    const float* __restrict__ b_free,
    float* __restrict__ p_out,     // [3][N][32]
    float* __restrict__ x2,        // [N][256]
    float* __restrict__ inv1,
    float* __restrict__ inv2,
    int N)
{
    int n = blockIdx.x;
    int t = threadIdx.x;
    __shared__ float xi[NF][32];
    __shared__ float ff[32];
    __shared__ float num_s[NF];
    __shared__ float red[64];

    for (int i = 0; i < NF; ++i) {
        float v = 0.f;
        if (t < 32) v = feats[((size_t)i*N + n)*32 + t];
        red[t] = v*v;
        __syncthreads();
        if (t == 0) { float s = 0.f; for (int c = 0; c < 32; ++c) s += red[c]; red[0] = s; }
        __syncthreads();
        float sumv2 = red[0];
        float k = ks[i];
        float xn = sqrtf(sumv2);
        float scale = 0.45f / (xn * sqrtf(fabsf(k)));   // (0.9*0.5)/(|x| sqrt|k|)
        if (t < 32) {
            float xv = v * scale;
            xi[i][t] = xv;
            p_out[((size_t)i*N + n)*32 + t] = xv;
        }
        if (t == 0) num_s[i] = 1.0f + k * (scale*scale*sumv2);
        __syncthreads();
    }
    if (t < 32) ff[t] = feat_free[(size_t)n*32 + t];
    __syncthreads();

    float zsq = 0.f;
    for (int i = 0; i < NF; ++i) {
        float div = 0.f;
        const float* wrow = Ws + ((size_t)i*DD + t)*32;
        #pragma unroll
        for (int c = 0; c < 32; ++c) { float d = xi[i][c] - wrow[c]; div += d*d; }
        float dist = logf(num_s[i] / (div + 1e-5f));
        float z = expf(15.5f * dist) * cosf(dist + bias[i*DD + t]);
        x2[(size_t)n*EMBED + i*DD + t] = z;
        zsq += z*z;
    }
    {
        float dot = 0.f;
        const float* wrow = W_free + (size_t)t*32;
        #pragma unroll
        for (int c = 0; c < 32; ++c) dot = fmaf(ff[c], wrow[c], dot);
        float z = expf(15.5f * dot) * cosf(dot + b_free[t]);
        x2[(size_t)n*EMBED + 192 + t] = z;
        zsq += z*z;
    }
    red[t] = zsq; __syncthreads();
    for (int s2 = 32; s2 > 0; s2 >>= 1) { if (t < s2) red[t] += red[t+s2]; __syncthreads(); }
    if (t == 0) inv2[n] = 1.0f / sqrtf(red[0]);
    __syncthreads();
    float s1 = 0.f;
    #pragma unroll
    for (int q = 0; q < 4; ++q) { float xv = x[(size_t)n*EMBED + q*64 + t]; s1 += xv*xv; }
    red[t] = s1; __syncthreads();
    for (int s2 = 32; s2 > 0; s2 >>= 1) { if (t < s2) red[t] += red[t+s2]; __syncthreads(); }
    if (t == 0) inv1[n] = 1.0f / sqrtf(red[0]);
}

// ---------------- Kernel 2: N x N exp(cos-sim/T), row/col sums + diag ---------
__global__ __launch_bounds__(256) void k_sim(
    const float* __restrict__ x, const float* __restrict__ x2,
    const float* __restrict__ inv1, const float* __restrict__ inv2,
    float* __restrict__ rowsum, float* __restrict__ colsum, float* __restrict__ pos,
    int N)
{
    __shared__ float As[BK][BM+4];
    __shared__ float Bs[BK][BN+4];
    __shared__ float rsum_s[BM];
    __shared__ float csum_s[BN];
    int tid = threadIdx.x;
    int tx = tid & 15, ty = tid >> 4;
    int row0 = blockIdx.y * BM, col0 = blockIdx.x * BN;
    float acc[8][8];
    #pragma unroll
    for (int i = 0; i < 8; ++i)
        #pragma unroll
        for (int j = 0; j < 8; ++j) acc[i][j] = 0.f;
    if (tid < BM) { rsum_s[tid] = 0.f; csum_s[tid] = 0.f; }

    int lr = tid >> 3;        // 0..31
    int lk = (tid & 7) * 4;   // 0,4,...,28
    for (int kt = 0; kt < EMBED; kt += BK) {
        #pragma unroll
        for (int it = 0; it < 4; ++it) {
            int r = lr + it*32;
            int gr = row0 + r;
            float4 v = make_float4(0.f,0.f,0.f,0.f);
            if (gr < N) v = *(const float4*)(x + (size_t)gr*EMBED + kt + lk);
            As[lk+0][r]=v.x; As[lk+1][r]=v.y; As[lk+2][r]=v.z; As[lk+3][r]=v.w;
            int gc = col0 + r;
            float4 w = make_float4(0.f,0.f,0.f,0.f);
            if (gc < N) w = *(const float4*)(x2 + (size_t)gc*EMBED + kt + lk);
            Bs[lk+0][r]=w.x; Bs[lk+1][r]=w.y; Bs[lk+2][r]=w.z; Bs[lk+3][r]=w.w;
        }
        __syncthreads();
        #pragma unroll
        for (int kk = 0; kk < BK; ++kk) {
            float4 a0 = *(const float4*)&As[kk][ty*8];
            float4 a1 = *(const float4*)&As[kk][ty*8+4];
            float4 b0 = *(const float4*)&Bs[kk][tx*8];
            float4 b1 = *(const float4*)&Bs[kk][tx*8+4];
            float a[8] = {a0.x,a0.y,a0.z,a0.w,a1.x,a1.y,a1.z,a1.w};
            float b[8] = {b0.x,b0.y,b0.z,b0.w,b1.x,b1.y,b1.z,b1.w};
            #pragma unroll
            for (int i = 0; i < 8; ++i)
                #pragma unroll
                for (int j = 0; j < 8; ++j) acc[i][j] = fmaf(a[i], b[j], acc[i][j]);
        }
        __syncthreads();
    }
    // epilogue: scale, exp, partial row/col sums
    float iv1[8], iv2[8];
    #pragma unroll
    for (int i = 0; i < 8; ++i) { int gi = row0 + ty*8 + i; iv1[i] = (gi < N) ? inv1[gi] : 0.f; }
    #pragma unroll
    for (int j = 0; j < 8; ++j) { int gj = col0 + tx*8 + j; iv2[j] = (gj < N) ? inv2[gj] : 0.f; }
    float rs[8] = {0,0,0,0,0,0,0,0}, cs[8] = {0,0,0,0,0,0,0,0};
    #pragma unroll
    for (int i = 0; i < 8; ++i) {
        int gi = row0 + ty*8 + i;
        #pragma unroll
        for (int j = 0; j < 8; ++j) {
            int gj = col0 + tx*8 + j;
            float e = 0.f;
            if (gi < N && gj < N) {
                float sim = acc[i][j] * iv1[i] * iv2[j];
                e = __expf(sim * 5.0f);          // /TEMP = *5
                if (gi == gj) pos[gi] = e;
            }
            rs[i] += e; cs[j] += e;
        }
    }
    #pragma unroll
    for (int i = 0; i < 8; ++i) atomicAdd(&rsum_s[ty*8 + i], rs[i]);
    #pragma unroll
    for (int j = 0; j < 8; ++j) atomicAdd(&csum_s[tx*8 + j], cs[j]);
    __syncthreads();
    if (tid < BM) {
        int gi = row0 + tid;
        if (gi < N) atomicAdd(&rowsum[gi], rsum_s[tid]);
        int gj = col0 + tid;
        if (gj < N) atomicAdd(&colsum[gj], csum_s[tid]);
    }
}

// ---------------- Kernel 3: motif MLP + BCE --------------------------------
// lanes = 64 hidden units; W1 column in VGPRs; row features via scalar loads.
__global__ __launch_bounds__(256) void k_motif(
    const float* __restrict__ p,        // [3][N][32]
    const float* __restrict__ feat_free,
    const int* __restrict__ motif,      // [3][M]
    const int* __restrict__ neg_uv,     // [2][M]
    const float* __restrict__ W1, const float* __restrict__ b1,
    const float* __restrict__ W2, const float* __restrict__ b2,
    float* __restrict__ acc_out, int N, int M)
{
    int wid  = (blockIdx.x * blockDim.x + threadIdx.x) >> 6;
    int lane = threadIdx.x & 63;
    int caseId = wid >> 8;          // 2048 waves / 8 cases = 256 waves each
    int wrank  = wid & 255;
    int prod  = caseId >> 1;
    int isneg = caseId & 1;
    const float* P = (prod < 3) ? (p + (size_t)prod * N * 32) : feat_free;

    float wcol[96];
    #pragma unroll
    for (int c = 0; c < 96; ++c) wcol[c] = W1[c*64 + lane];
    float w2  = W2[lane];
    float b1l = b1[lane];
    float b2v = b2[0];

    float accl = 0.f;
    for (int r = wrank; r < M; r += 256) {
        int u, v, w;
        if (isneg) { u = neg_uv[r]; v = neg_uv[M + r]; }
        else       { u = motif[r];  v = motif[M + r]; }
        w = motif[2*M + r];
        u = __builtin_amdgcn_readfirstlane(u);
        v = __builtin_amdgcn_readfirstlane(v);
        w = __builtin_amdgcn_readfirstlane(w);
        const float* fu = P + (size_t)u*32;
        const float* fv = P + (size_t)v*32;
        const float* fw = P + (size_t)w*32;
        float h = b1l;
        #pragma unroll
        for (int c = 0; c < 32; ++c) h = fmaf(fu[c], wcol[c],    h);
        #pragma unroll
        for (int c = 0; c < 32; ++c) h = fmaf(fv[c], wcol[32+c], h);
        #pragma unroll
        for (int c = 0; c < 32; ++c) h = fmaf(fw[c], wcol[64+c], h);
        h = fmaxf(h, 0.f);
        float pl = h * w2;
        #pragma unroll
        for (int m = 1; m < 64; m <<= 1) pl += __shfl_xor(pl, m, 64);
        float logit = pl + b2v;
        float z = isneg ? -logit : logit;
        // log_sigmoid(z) = -softplus(-z)
        float tn = -z;
        float sp = fmaxf(tn, 0.f) + log1pf(expf(-fabsf(tn)));
        if (lane == 0) accl -= sp;
    }
    if (lane == 0) atomicAdd(acc_out, accl);
}

// ---------------- Kernel 4: final scalar assembly ---------------------------
__global__ __launch_bounds__(256) void k_final(
    const float* __restrict__ rowsum, const float* __restrict__ colsum,
    const float* __restrict__ pos, const float* __restrict__ acc_motif,
    float* __restrict__ out, int N, int M)
{
    __shared__ float red1[256], red2[256];
    int t = threadIdx.x;
    float l1 = 0.f, l2 = 0.f;
    for (int i = t; i < N; i += 256) {
        float pv = pos[i];
        l1 += logf((colsum[i] - pv) / pv);   // -log(pos/(colsum-pos))
        l2 += logf((rowsum[i] - pv) / pv);
    }
    red1[t] = l1; red2[t] = l2; __syncthreads();
    for (int s = 128; s > 0; s >>= 1) {
        if (t < s) { red1[t] += red1[t+s]; red2[t] += red2[t+s]; }
        __syncthreads();
    }
    if (t == 0) {
        float cl = 0.5f * (red1[0] + red2[0]) / (float)N;
        out[0] = cl - acc_motif[0] / (float)M;   // motif_loss = -sum(ls)/M
    }
}

extern "C" void kernel_launch(void* const* d_in, const int* in_sizes, int n_in,
                              void* d_out, int out_size, void* d_ws, size_t ws_size,
                              hipStream_t stream)
{
    const float* x         = (const float*)d_in[0];
    const float* feats     = (const float*)d_in[1];
    const float* feat_free = (const float*)d_in[2];
    const float* ks        = (const float*)d_in[3];
    const float* Ws        = (const float*)d_in[4];
    const float* bias      = (const float*)d_in[5];
    const float* W_free    = (const float*)d_in[6];
    const float* b_free    = (const float*)d_in[7];
    const float* W1        = (const float*)d_in[8];
    const float* b1        = (const float*)d_in[9];
    const float* W2        = (const float*)d_in[10];
    const float* b2        = (const float*)d_in[11];
    const int*   motif     = (const int*)d_in[12];
    const int*   neg_uv    = (const int*)d_in[13];
    int N = in_sizes[0] / EMBED;          // 10000
    int M = in_sizes[13] / 2;             // 50000

    float* W      = (float*)d_ws;
    float* x2     = W;                               // N*256
    float* p      = x2 + (size_t)N*EMBED;            // 3*N*32
    float* inv1   = p + (size_t)3*N*32;              // N
    float* inv2   = inv1 + N;                        // N
    float* posv   = inv2 + N;                        // N
    float* rowsum = posv + N;                        // N
    float* colsum = rowsum + N;                      // N
    float* accm   = colsum + N;                      // 1

    hipMemsetAsync(rowsum, 0, (size_t)(2*N + 1) * sizeof(float), stream);

    k_embed<<<N, 64, 0, stream>>>(x, feats, feat_free, ks, Ws, bias, W_free, b_free,
                                  p, x2, inv1, inv2, N);
    k_motif<<<512, 256, 0, stream>>>(p, feat_free, motif, neg_uv, W1, b1, W2, b2,
                                     accm, N, M);
    int nb = (N + BM - 1) / BM;
    k_sim<<<dim3(nb, nb), 256, 0, stream>>>(x, x2, inv1, inv2, rowsum, colsum, posv, N);
    k_final<<<1, 256, 0, stream>>>(rowsum, colsum, posv, accm, (float*)d_out, N, M);
}

// Round 2
// 619.095 us; speedup vs baseline: 2.0258x; 2.0258x over previous
//
#include <hip/hip_runtime.h>
#include <hip/hip_bf16.h>
#include <math.h>

#define EMBED 256
#define NF 3
#define DD 64
#define BM 128
#define BN 128
#define BK 32

typedef unsigned short ushort_t;
typedef __bf16 bf16x8 __attribute__((ext_vector_type(8)));
typedef float f32x4 __attribute__((ext_vector_type(4)));

__device__ __forceinline__ void gl2lds16(const ushort_t* g, ushort_t* l) {
    __builtin_amdgcn_global_load_lds(
        (const __attribute__((address_space(1))) unsigned int*)g,
        (__attribute__((address_space(3))) unsigned int*)l, 16, 0, 0);
}

__device__ __forceinline__ ushort_t f2bf(float f) {
    __hip_bfloat16 h = __float2bfloat16(f);
    return *(ushort_t*)&h;
}

// ---------------- Kernel 1: normalize + random_mapping -> bf16-normalized xn/x2n, p ----
__global__ __launch_bounds__(64) void k_embed(
    const float* __restrict__ x,
    const float* __restrict__ feats,
    const float* __restrict__ feat_free,
    const float* __restrict__ ks,
    const float* __restrict__ Ws,
    const float* __restrict__ bias,
    const float* __restrict__ W_free,
    const float* __restrict__ b_free,
    float* __restrict__ p_out,        // [3][N][32]
    ushort_t* __restrict__ xnbf,      // [Npad][256] bf16, row-normalized x
    ushort_t* __restrict__ x2nbf,     // [Npad][256] bf16, row-normalized x2
    int N)
{
    int n = blockIdx.x;
    int t = threadIdx.x;
    __shared__ float xi[NF][32];
    __shared__ float ff[32];
    __shared__ float num_s[NF];
    __shared__ float red[64];

    for (int i = 0; i < NF; ++i) {
        float v = 0.f;
        if (t < 32) v = feats[((size_t)i*N + n)*32 + t];
        red[t] = v*v;
        __syncthreads();
        if (t == 0) { float s = 0.f; for (int c = 0; c < 32; ++c) s += red[c]; red[0] = s; }
        __syncthreads();
        float sumv2 = red[0];
        float k = ks[i];
        float xn = sqrtf(sumv2);
        float scale = 0.45f / (xn * sqrtf(fabsf(k)));   // (0.9*0.5)/(|x| sqrt|k|)
        if (t < 32) {
            float xv = v * scale;
            xi[i][t] = xv;
            p_out[((size_t)i*N + n)*32 + t] = xv;
        }
        if (t == 0) num_s[i] = 1.0f + k * (scale*scale*sumv2);
        __syncthreads();
    }
    if (t < 32) ff[t] = feat_free[(size_t)n*32 + t];
    __syncthreads();

    float z[4];
    float zsq = 0.f;
    for (int i = 0; i < NF; ++i) {
        float div = 0.f;
        const float* wrow = Ws + ((size_t)i*DD + t)*32;
        #pragma unroll
        for (int c = 0; c < 32; ++c) { float d = xi[i][c] - wrow[c]; div += d*d; }
        float dist = logf(num_s[i] / (div + 1e-5f));
        float zz = expf(15.5f * dist) * cosf(dist + bias[i*DD + t]);
        z[i] = zz;
        zsq += zz*zz;
    }
    {
        float dot = 0.f;
        const float* wrow = W_free + (size_t)t*32;
        #pragma unroll
        for (int c = 0; c < 32; ++c) dot = fmaf(ff[c], wrow[c], dot);
        float zz = expf(15.5f * dot) * cosf(dot + b_free[t]);
        z[3] = zz;
        zsq += zz*zz;
    }
    red[t] = zsq; __syncthreads();
    for (int s2 = 32; s2 > 0; s2 >>= 1) { if (t < s2) red[t] += red[t+s2]; __syncthreads(); }
    float iv2 = 1.0f / sqrtf(red[0]);
    __syncthreads();

    #pragma unroll
    for (int i = 0; i < NF; ++i) x2nbf[(size_t)n*EMBED + i*DD + t] = f2bf(z[i]*iv2);
    x2nbf[(size_t)n*EMBED + 192 + t] = f2bf(z[3]*iv2);

    float xv[4];
    float s1 = 0.f;
    #pragma unroll
    for (int q = 0; q < 4; ++q) { xv[q] = x[(size_t)n*EMBED + q*64 + t]; s1 += xv[q]*xv[q]; }
    red[t] = s1; __syncthreads();
    for (int s2 = 32; s2 > 0; s2 >>= 1) { if (t < s2) red[t] += red[t+s2]; __syncthreads(); }
    float iv1 = 1.0f / sqrtf(red[0]);
    #pragma unroll
    for (int q = 0; q < 4; ++q) xnbf[(size_t)n*EMBED + q*64 + t] = f2bf(xv[q]*iv1);
}

// ---------------- Kernel 2: bf16 MFMA GEMM, exp(5*sim), row/col sums + diag ---------
__global__ __launch_bounds__(256) void k_sim(
    const ushort_t* __restrict__ xn, const ushort_t* __restrict__ x2n,
    float* __restrict__ rowsum, float* __restrict__ colsum, float* __restrict__ pos,
    int N)
{
    __shared__ ushort_t As[BM*BK];   // [row][k] row-major, 64B rows
    __shared__ ushort_t Bs[BN*BK];
    __shared__ float rsum_s[BM];
    __shared__ float csum_s[BN];

    int tid  = threadIdx.x;
    int lane = tid & 63;
    int w    = tid >> 6;
    int wr   = w >> 1, wc = w & 1;
    int quad = lane >> 4, l15 = lane & 15;
    int row0 = blockIdx.y * BM, col0 = blockIdx.x * BN;

    if (tid < BM) { rsum_s[tid] = 0.f; csum_s[tid] = 0.f; }

    f32x4 acc[4][4];
    #pragma unroll
    for (int i = 0; i < 4; ++i)
        #pragma unroll
        for (int j = 0; j < 4; ++j) acc[i][j] = (f32x4){0.f,0.f,0.f,0.f};

    int srow = tid >> 2;          // 0..63
    int sch  = (tid & 3) * 8;     // k-element chunk (8 bf16 = 16B)
    for (int kt = 0; kt < EMBED; kt += BK) {
        #pragma unroll
        for (int it = 0; it < 2; ++it) {
            const ushort_t* ga = xn  + ((size_t)(row0 + it*64 + srow))*EMBED + kt + sch;
            gl2lds16(ga, &As[it*2048 + tid*8]);
            const ushort_t* gb = x2n + ((size_t)(col0 + it*64 + srow))*EMBED + kt + sch;
            gl2lds16(gb, &Bs[it*2048 + tid*8]);
        }
        __syncthreads();
        bf16x8 a[4], b[4];
        #pragma unroll
        for (int ti = 0; ti < 4; ++ti)
            a[ti] = *(const bf16x8*)&As[(wr*64 + ti*16 + l15)*BK + quad*8];
        #pragma unroll
        for (int tj = 0; tj < 4; ++tj)
            b[tj] = *(const bf16x8*)&Bs[(wc*64 + tj*16 + l15)*BK + quad*8];
        #pragma unroll
        for (int ti = 0; ti < 4; ++ti)
            #pragma unroll
            for (int tj = 0; tj < 4; ++tj)
                acc[ti][tj] = __builtin_amdgcn_mfma_f32_16x16x32_bf16(a[ti], b[tj], acc[ti][tj], 0, 0, 0);
        __syncthreads();
    }

    // epilogue: e = exp(5*sim) (operands pre-normalized), diag, row/col partials
    #pragma unroll
    for (int ti = 0; ti < 4; ++ti) {
        #pragma unroll
        for (int tj = 0; tj < 4; ++tj) {
            #pragma unroll
            for (int r = 0; r < 4; ++r) {
                int gi = row0 + wr*64 + ti*16 + quad*4 + r;
                int gj = col0 + wc*64 + tj*16 + l15;
                float e = 0.f;
                if (gi < N && gj < N) {
                    e = __expf(acc[ti][tj][r] * 5.0f);
                    if (gi == gj) pos[gi] = e;
                }
                acc[ti][tj][r] = e;
            }
        }
    }
    // row sums: reduce 16 cols across lanes (xor 1,2,4,8)
    #pragma unroll
    for (int ti = 0; ti < 4; ++ti) {
        #pragma unroll
        for (int r = 0; r < 4; ++r) {
            float rsv = acc[ti][0][r] + acc[ti][1][r] + acc[ti][2][r] + acc[ti][3][r];
            rsv += __shfl_xor(rsv, 1, 64);
            rsv += __shfl_xor(rsv, 2, 64);
            rsv += __shfl_xor(rsv, 4, 64);
            rsv += __shfl_xor(rsv, 8, 64);
            if (l15 == 0) atomicAdd(&rsum_s[wr*64 + ti*16 + quad*4 + r], rsv);
        }
    }
    // col sums: reduce rows across quads (xor 16,32)
    #pragma unroll
    for (int tj = 0; tj < 4; ++tj) {
        float csv = 0.f;
        #pragma unroll
        for (int ti = 0; ti < 4; ++ti)
            #pragma unroll
            for (int r = 0; r < 4; ++r) csv += acc[ti][tj][r];
        csv += __shfl_xor(csv, 16, 64);
        csv += __shfl_xor(csv, 32, 64);
        if (lane < 16) atomicAdd(&csum_s[wc*64 + tj*16 + lane], csv);
    }
    __syncthreads();
    if (tid < BM) {
        int gi = row0 + tid;
        if (gi < N) atomicAdd(&rowsum[gi], rsum_s[tid]);
        int gj = col0 + tid;
        if (gj < N) atomicAdd(&colsum[gj], csum_s[tid]);
    }
}

// ---------------- Kernel 3: motif MLP + BCE --------------------------------
__global__ __launch_bounds__(256) void k_motif(
    const float* __restrict__ p,        // [3][N][32]
    const float* __restrict__ feat_free,
    const int* __restrict__ motif,      // [3][M]
    const int* __restrict__ neg_uv,     // [2][M]
    const float* __restrict__ W1, const float* __restrict__ b1,
    const float* __restrict__ W2, const float* __restrict__ b2,
    float* __restrict__ acc_out, int N, int M)
{
    int wid  = (blockIdx.x * blockDim.x + threadIdx.x) >> 6;
    int lane = threadIdx.x & 63;
    int caseId = wid >> 8;          // 2048 waves / 8 cases = 256 waves each
    int wrank  = wid & 255;
    int prod  = caseId >> 1;
    int isneg = caseId & 1;
    const float* P = (prod < 3) ? (p + (size_t)prod * N * 32) : feat_free;

    float wcol[96];
    #pragma unroll
    for (int c = 0; c < 96; ++c) wcol[c] = W1[c*64 + lane];
    float w2  = W2[lane];
    float b1l = b1[lane];
    float b2v = b2[0];

    float accl = 0.f;
    for (int r = wrank; r < M; r += 256) {
        int u, v, w;
        if (isneg) { u = neg_uv[r]; v = neg_uv[M + r]; }
        else       { u = motif[r];  v = motif[M + r]; }
        w = motif[2*M + r];
        u = __builtin_amdgcn_readfirstlane(u);
        v = __builtin_amdgcn_readfirstlane(v);
        w = __builtin_amdgcn_readfirstlane(w);
        const float* fu = P + (size_t)u*32;
        const float* fv = P + (size_t)v*32;
        const float* fw = P + (size_t)w*32;
        float h = b1l;
        #pragma unroll
        for (int c = 0; c < 32; ++c) h = fmaf(fu[c], wcol[c],    h);
        #pragma unroll
        for (int c = 0; c < 32; ++c) h = fmaf(fv[c], wcol[32+c], h);
        #pragma unroll
        for (int c = 0; c < 32; ++c) h = fmaf(fw[c], wcol[64+c], h);
        h = fmaxf(h, 0.f);
        float pl = h * w2;
        #pragma unroll
        for (int m = 1; m < 64; m <<= 1) pl += __shfl_xor(pl, m, 64);
        float logit = pl + b2v;
        float z = isneg ? -logit : logit;
        float tn = -z;
        float sp = fmaxf(tn, 0.f) + log1pf(expf(-fabsf(tn)));
        if (lane == 0) accl -= sp;
    }
    if (lane == 0) atomicAdd(acc_out, accl);
}

// ---------------- Kernel 4: final scalar assembly ---------------------------
__global__ __launch_bounds__(256) void k_final(
    const float* __restrict__ rowsum, const float* __restrict__ colsum,
    const float* __restrict__ pos, const float* __restrict__ acc_motif,
    float* __restrict__ out, int N, int M)
{
    __shared__ float red1[256], red2[256];
    int t = threadIdx.x;
    float l1 = 0.f, l2 = 0.f;
    for (int i = t; i < N; i += 256) {
        float pv = pos[i];
        l1 += logf((colsum[i] - pv) / pv);
        l2 += logf((rowsum[i] - pv) / pv);
    }
    red1[t] = l1; red2[t] = l2; __syncthreads();
    for (int s = 128; s > 0; s >>= 1) {
        if (t < s) { red1[t] += red1[t+s]; red2[t] += red2[t+s]; }
        __syncthreads();
    }
    if (t == 0) {
        float cl = 0.5f * (red1[0] + red2[0]) / (float)N;
        out[0] = cl - acc_motif[0] / (float)M;
    }
}

extern "C" void kernel_launch(void* const* d_in, const int* in_sizes, int n_in,
                              void* d_out, int out_size, void* d_ws, size_t ws_size,
                              hipStream_t stream)
{
    const float* x         = (const float*)d_in[0];
    const float* feats     = (const float*)d_in[1];
    const float* feat_free = (const float*)d_in[2];
    const float* ks        = (const float*)d_in[3];
    const float* Ws        = (const float*)d_in[4];
    const float* bias      = (const float*)d_in[5];
    const float* W_free    = (const float*)d_in[6];
    const float* b_free    = (const float*)d_in[7];
    const float* W1        = (const float*)d_in[8];
    const float* b1        = (const float*)d_in[9];
    const float* W2        = (const float*)d_in[10];
    const float* b2        = (const float*)d_in[11];
    const int*   motif     = (const int*)d_in[12];
    const int*   neg_uv    = (const int*)d_in[13];
    int N = in_sizes[0] / EMBED;          // 10000
    int M = in_sizes[13] / 2;             // 50000
    int nb = (N + BM - 1) / BM;           // 79
    int Npad = nb * BM;                   // 10112

    ushort_t* xnbf  = (ushort_t*)d_ws;                     // Npad*256 bf16
    ushort_t* x2nbf = xnbf + (size_t)Npad*EMBED;           // Npad*256 bf16
    float* p      = (float*)(x2nbf + (size_t)Npad*EMBED);  // 3*N*32
    float* posv   = p + (size_t)3*N*32;                    // N
    float* rowsum = posv + N;                              // N
    float* colsum = rowsum + N;                            // N
    float* accm   = colsum + N;                            // 1

    hipMemsetAsync(rowsum, 0, (size_t)(2*N + 1) * sizeof(float), stream);
    // zero pad-tail rows of the bf16 operand buffers
    hipMemsetAsync(xnbf  + (size_t)N*EMBED, 0, (size_t)(Npad - N)*EMBED*sizeof(ushort_t), stream);
    hipMemsetAsync(x2nbf + (size_t)N*EMBED, 0, (size_t)(Npad - N)*EMBED*sizeof(ushort_t), stream);

    k_embed<<<N, 64, 0, stream>>>(x, feats, feat_free, ks, Ws, bias, W_free, b_free,
                                  p, xnbf, x2nbf, N);
    k_motif<<<512, 256, 0, stream>>>(p, feat_free, motif, neg_uv, W1, b1, W2, b2,
                                     accm, N, M);
    k_sim<<<dim3(nb, nb), 256, 0, stream>>>(xnbf, x2nbf, rowsum, colsum, posv, N);
    k_final<<<1, 256, 0, stream>>>(rowsum, colsum, posv, accm, (float*)d_out, N, M);
}

// Round 3
// 474.446 us; speedup vs baseline: 2.6434x; 1.3049x over previous
//
#include <hip/hip_runtime.h>
#include <hip/hip_bf16.h>
#include <math.h>

#define EMBED 256
#define NF 3
#define DD 64
#define BM 128
#define BN 128
#define BK 32

typedef unsigned short ushort_t;
typedef __bf16 bf16x8 __attribute__((ext_vector_type(8)));
typedef float f32x4 __attribute__((ext_vector_type(4)));

__device__ __forceinline__ void gl2lds16(const ushort_t* g, ushort_t* l) {
    __builtin_amdgcn_global_load_lds(
        (const __attribute__((address_space(1))) unsigned int*)g,
        (__attribute__((address_space(3))) unsigned int*)l, 16, 0, 0);
}

__device__ __forceinline__ ushort_t f2bf(float f) {
    __hip_bfloat16 h = __float2bfloat16(f);
    return *(ushort_t*)&h;
}
__device__ __forceinline__ float bf2f(ushort_t u) {
    unsigned int w = ((unsigned int)u) << 16;
    return __builtin_bit_cast(float, w);
}

// ---------------- Kernel 1: normalize + random_mapping -> bf16-normalized xn/x2n, p ----
__global__ __launch_bounds__(64) void k_embed(
    const float* __restrict__ x,
    const float* __restrict__ feats,
    const float* __restrict__ feat_free,
    const float* __restrict__ ks,
    const float* __restrict__ Ws,
    const float* __restrict__ bias,
    const float* __restrict__ W_free,
    const float* __restrict__ b_free,
    float* __restrict__ p_out,        // [3][N][32]
    ushort_t* __restrict__ xnbf,      // [Npad][256] bf16, row-normalized x
    ushort_t* __restrict__ x2nbf,     // [Npad][256] bf16, row-normalized x2
    int N)
{
    int n = blockIdx.x;
    int t = threadIdx.x;
    __shared__ float xi[NF][32];
    __shared__ float ff[32];
    __shared__ float num_s[NF];
    __shared__ float red[64];

    for (int i = 0; i < NF; ++i) {
        float v = 0.f;
        if (t < 32) v = feats[((size_t)i*N + n)*32 + t];
        red[t] = v*v;
        __syncthreads();
        if (t == 0) { float s = 0.f; for (int c = 0; c < 32; ++c) s += red[c]; red[0] = s; }
        __syncthreads();
        float sumv2 = red[0];
        float k = ks[i];
        float xn = sqrtf(sumv2);
        float scale = 0.45f / (xn * sqrtf(fabsf(k)));   // (0.9*0.5)/(|x| sqrt|k|)
        if (t < 32) {
            float xv = v * scale;
            xi[i][t] = xv;
            p_out[((size_t)i*N + n)*32 + t] = xv;
        }
        if (t == 0) num_s[i] = 1.0f + k * (scale*scale*sumv2);
        __syncthreads();
    }
    if (t < 32) ff[t] = feat_free[(size_t)n*32 + t];
    __syncthreads();

    float z[4];
    float zsq = 0.f;
    for (int i = 0; i < NF; ++i) {
        float div = 0.f;
        const float* wrow = Ws + ((size_t)i*DD + t)*32;
        #pragma unroll
        for (int c = 0; c < 32; ++c) { float d = xi[i][c] - wrow[c]; div += d*d; }
        float dist = logf(num_s[i] / (div + 1e-5f));
        float zz = expf(15.5f * dist) * cosf(dist + bias[i*DD + t]);
        z[i] = zz;
        zsq += zz*zz;
    }
    {
        float dot = 0.f;
        const float* wrow = W_free + (size_t)t*32;
        #pragma unroll
        for (int c = 0; c < 32; ++c) dot = fmaf(ff[c], wrow[c], dot);
        float zz = expf(15.5f * dot) * cosf(dot + b_free[t]);
        z[3] = zz;
        zsq += zz*zz;
    }
    red[t] = zsq; __syncthreads();
    for (int s2 = 32; s2 > 0; s2 >>= 1) { if (t < s2) red[t] += red[t+s2]; __syncthreads(); }
    float iv2 = 1.0f / sqrtf(red[0]);
    __syncthreads();

    #pragma unroll
    for (int i = 0; i < NF; ++i) x2nbf[(size_t)n*EMBED + i*DD + t] = f2bf(z[i]*iv2);
    x2nbf[(size_t)n*EMBED + 192 + t] = f2bf(z[3]*iv2);

    float xv[4];
    float s1 = 0.f;
    #pragma unroll
    for (int q = 0; q < 4; ++q) { xv[q] = x[(size_t)n*EMBED + q*64 + t]; s1 += xv[q]*xv[q]; }
    red[t] = s1; __syncthreads();
    for (int s2 = 32; s2 > 0; s2 >>= 1) { if (t < s2) red[t] += red[t+s2]; __syncthreads(); }
    float iv1 = 1.0f / sqrtf(red[0]);
    #pragma unroll
    for (int q = 0; q < 4; ++q) xnbf[(size_t)n*EMBED + q*64 + t] = f2bf(xv[q]*iv1);
}

// ---------------- Kernel 2: per-node MLP hidden partials --------------------
// H[prod][slot][node][lane] = sum_c P_prod[node][c] * W1[slot*32+c][lane]  (bf16)
__global__ __launch_bounds__(256) void k_mlp1(
    const float* __restrict__ p,          // [3][N][32]
    const float* __restrict__ feat_free,  // [N][32]
    const float* __restrict__ W1,         // [96][64]
    ushort_t* __restrict__ H,             // [4][3][N][64]
    int N)
{
    int lane = threadIdx.x & 63;
    int gw = (blockIdx.x * blockDim.x + threadIdx.x) >> 6;
    int nwaves = (gridDim.x * blockDim.x) >> 6;

    float wcol[96];
    #pragma unroll
    for (int c = 0; c < 96; ++c) wcol[c] = W1[c*64 + lane];

    int total = 4 * N;
    for (int unit = gw; unit < total; unit += nwaves) {
        int node = __builtin_amdgcn_readfirstlane(unit >> 2);
        int prod = __builtin_amdgcn_readfirstlane(unit & 3);
        const float* P = (prod < 3) ? (p + ((size_t)prod*N + node)*32)
                                    : (feat_free + (size_t)node*32);
        float fc[32];
        #pragma unroll
        for (int c = 0; c < 32; ++c) fc[c] = P[c];
        #pragma unroll
        for (int s = 0; s < 3; ++s) {
            float h = 0.f;
            #pragma unroll
            for (int c = 0; c < 32; ++c) h = fmaf(fc[c], wcol[s*32 + c], h);
            H[(((size_t)prod*3 + s)*N + node)*64 + lane] = f2bf(h);
        }
    }
}

// ---------------- Kernel 3: motif loss from gathered partials ---------------
__global__ __launch_bounds__(256) void k_motif2(
    const ushort_t* __restrict__ H,       // [4][3][N][64]
    const int* __restrict__ motif,        // [3][M]
    const int* __restrict__ neg_uv,       // [2][M]
    const float* __restrict__ b1,
    const float* __restrict__ W2,
    const float* __restrict__ b2,
    float* __restrict__ acc_out, int N, int M)
{
    int lane = threadIdx.x & 63;
    int gw = (blockIdx.x * blockDim.x + threadIdx.x) >> 6;
    // 8192 waves: 1024 per case
    int caseId = gw >> 10;
    int rank   = gw & 1023;
    int prod  = caseId >> 1;
    int isneg = caseId & 1;
    const ushort_t* Hu = H + ((size_t)prod*3 + 0)*N*64;
    const ushort_t* Hv = H + ((size_t)prod*3 + 1)*N*64;
    const ushort_t* Hw = H + ((size_t)prod*3 + 2)*N*64;
    const int* iu = isneg ? neg_uv       : motif;
    const int* iv = isneg ? (neg_uv + M) : (motif + M);
    const int* iw = motif + 2*M;

    float b1l = b1[lane];
    float w2l = W2[lane];
    float b2v = b2[0];

    float accl = 0.f;
    #pragma unroll 2
    for (int r = rank; r < M; r += 1024) {
        int u = __builtin_amdgcn_readfirstlane(iu[r]);
        int v = __builtin_amdgcn_readfirstlane(iv[r]);
        int w = __builtin_amdgcn_readfirstlane(iw[r]);
        float hu = bf2f(Hu[(size_t)u*64 + lane]);
        float hv = bf2f(Hv[(size_t)v*64 + lane]);
        float hw = bf2f(Hw[(size_t)w*64 + lane]);
        float h = fmaxf(b1l + hu + hv + hw, 0.f);
        float pl = h * w2l;
        #pragma unroll
        for (int m = 1; m < 64; m <<= 1) pl += __shfl_xor(pl, m, 64);
        float logit = pl + b2v;
        float z = isneg ? -logit : logit;
        // -log_sigmoid(z) = softplus(-z)
        float sp = fmaxf(-z, 0.f) + log1pf(expf(-fabsf(z)));
        if (lane == 0) accl -= sp;
    }
    if (lane == 0) atomicAdd(acc_out, accl);
}

// ---------------- Kernel 4: bf16 MFMA GEMM, exp(5*sim), row/col sums + diag ---------
__global__ __launch_bounds__(256) void k_sim(
    const ushort_t* __restrict__ xn, const ushort_t* __restrict__ x2n,
    float* __restrict__ rowsum, float* __restrict__ colsum, float* __restrict__ pos,
    int N)
{
    __shared__ ushort_t As[BM*BK];   // [row][k] row-major, 64B rows
    __shared__ ushort_t Bs[BN*BK];
    __shared__ float rsum_s[BM];
    __shared__ float csum_s[BN];

    int tid  = threadIdx.x;
    int lane = tid & 63;
    int w    = tid >> 6;
    int wr   = w >> 1, wc = w & 1;
    int quad = lane >> 4, l15 = lane & 15;
    int row0 = blockIdx.y * BM, col0 = blockIdx.x * BN;

    if (tid < BM) { rsum_s[tid] = 0.f; csum_s[tid] = 0.f; }

    f32x4 acc[4][4];
    #pragma unroll
    for (int i = 0; i < 4; ++i)
        #pragma unroll
        for (int j = 0; j < 4; ++j) acc[i][j] = (f32x4){0.f,0.f,0.f,0.f};

    int srow = tid >> 2;          // 0..63
    int sch  = (tid & 3) * 8;     // k-element chunk (8 bf16 = 16B)
    for (int kt = 0; kt < EMBED; kt += BK) {
        #pragma unroll
        for (int it = 0; it < 2; ++it) {
            const ushort_t* ga = xn  + ((size_t)(row0 + it*64 + srow))*EMBED + kt + sch;
            gl2lds16(ga, &As[it*2048 + tid*8]);
            const ushort_t* gb = x2n + ((size_t)(col0 + it*64 + srow))*EMBED + kt + sch;
            gl2lds16(gb, &Bs[it*2048 + tid*8]);
        }
        __syncthreads();
        bf16x8 a[4], b[4];
        #pragma unroll
        for (int ti = 0; ti < 4; ++ti)
            a[ti] = *(const bf16x8*)&As[(wr*64 + ti*16 + l15)*BK + quad*8];
        #pragma unroll
        for (int tj = 0; tj < 4; ++tj)
            b[tj] = *(const bf16x8*)&Bs[(wc*64 + tj*16 + l15)*BK + quad*8];
        #pragma unroll
        for (int ti = 0; ti < 4; ++ti)
            #pragma unroll
            for (int tj = 0; tj < 4; ++tj)
                acc[ti][tj] = __builtin_amdgcn_mfma_f32_16x16x32_bf16(a[ti], b[tj], acc[ti][tj], 0, 0, 0);
        __syncthreads();
    }

    // epilogue: e = exp(5*sim) (operands pre-normalized), diag, row/col partials
    #pragma unroll
    for (int ti = 0; ti < 4; ++ti) {
        #pragma unroll
        for (int tj = 0; tj < 4; ++tj) {
            #pragma unroll
            for (int r = 0; r < 4; ++r) {
                int gi = row0 + wr*64 + ti*16 + quad*4 + r;
                int gj = col0 + wc*64 + tj*16 + l15;
                float e = 0.f;
                if (gi < N && gj < N) {
                    e = __expf(acc[ti][tj][r] * 5.0f);
                    if (gi == gj) pos[gi] = e;
                }
                acc[ti][tj][r] = e;
            }
        }
    }
    #pragma unroll
    for (int ti = 0; ti < 4; ++ti) {
        #pragma unroll
        for (int r = 0; r < 4; ++r) {
            float rsv = acc[ti][0][r] + acc[ti][1][r] + acc[ti][2][r] + acc[ti][3][r];
            rsv += __shfl_xor(rsv, 1, 64);
            rsv += __shfl_xor(rsv, 2, 64);
            rsv += __shfl_xor(rsv, 4, 64);
            rsv += __shfl_xor(rsv, 8, 64);
            if (l15 == 0) atomicAdd(&rsum_s[wr*64 + ti*16 + quad*4 + r], rsv);
        }
    }
    #pragma unroll
    for (int tj = 0; tj < 4; ++tj) {
        float csv = 0.f;
        #pragma unroll
        for (int ti = 0; ti < 4; ++ti)
            #pragma unroll
            for (int r = 0; r < 4; ++r) csv += acc[ti][tj][r];
        csv += __shfl_xor(csv, 16, 64);
        csv += __shfl_xor(csv, 32, 64);
        if (lane < 16) atomicAdd(&csum_s[wc*64 + tj*16 + lane], csv);
    }
    __syncthreads();
    if (tid < BM) {
        int gi = row0 + tid;
        if (gi < N) atomicAdd(&rowsum[gi], rsum_s[tid]);
        int gj = col0 + tid;
        if (gj < N) atomicAdd(&colsum[gj], csum_s[tid]);
    }
}

// ---------------- Kernel 5: final scalar assembly ---------------------------
__global__ __launch_bounds__(256) void k_final(
    const float* __restrict__ rowsum, const float* __restrict__ colsum,
    const float* __restrict__ pos, const float* __restrict__ acc_motif,
    float* __restrict__ out, int N, int M)
{
    __shared__ float red1[256], red2[256];
    int t = threadIdx.x;
    float l1 = 0.f, l2 = 0.f;
    for (int i = t; i < N; i += 256) {
        float pv = pos[i];
        l1 += logf((colsum[i] - pv) / pv);
        l2 += logf((rowsum[i] - pv) / pv);
    }
    red1[t] = l1; red2[t] = l2; __syncthreads();
    for (int s = 128; s > 0; s >>= 1) {
        if (t < s) { red1[t] += red1[t+s]; red2[t] += red2[t+s]; }
        __syncthreads();
    }
    if (t == 0) {
        float cl = 0.5f * (red1[0] + red2[0]) / (float)N;
        out[0] = cl - acc_motif[0] / (float)M;
    }
}

extern "C" void kernel_launch(void* const* d_in, const int* in_sizes, int n_in,
                              void* d_out, int out_size, void* d_ws, size_t ws_size,
                              hipStream_t stream)
{
    const float* x         = (const float*)d_in[0];
    const float* feats     = (const float*)d_in[1];
    const float* feat_free = (const float*)d_in[2];
    const float* ks        = (const float*)d_in[3];
    const float* Ws        = (const float*)d_in[4];
    const float* bias      = (const float*)d_in[5];
    const float* W_free    = (const float*)d_in[6];
    const float* b_free    = (const float*)d_in[7];
    const float* W1        = (const float*)d_in[8];
    const float* b1        = (const float*)d_in[9];
    const float* W2        = (const float*)d_in[10];
    const float* b2        = (const float*)d_in[11];
    const int*   motif     = (const int*)d_in[12];
    const int*   neg_uv    = (const int*)d_in[13];
    int N = in_sizes[0] / EMBED;          // 10000
    int M = in_sizes[13] / 2;             // 50000
    int nb = (N + BM - 1) / BM;           // 79
    int Npad = nb * BM;                   // 10112

    ushort_t* xnbf  = (ushort_t*)d_ws;                     // Npad*256 bf16
    ushort_t* x2nbf = xnbf + (size_t)Npad*EMBED;           // Npad*256 bf16
    ushort_t* H     = x2nbf + (size_t)Npad*EMBED;          // 12*N*64 bf16
    float* p      = (float*)(H + (size_t)12*N*64);         // 3*N*32
    float* posv   = p + (size_t)3*N*32;                    // N
    float* rowsum = posv + N;                              // N
    float* colsum = rowsum + N;                            // N
    float* accm   = colsum + N;                            // 1

    hipMemsetAsync(rowsum, 0, (size_t)(2*N + 1) * sizeof(float), stream);
    hipMemsetAsync(xnbf  + (size_t)N*EMBED, 0, (size_t)(Npad - N)*EMBED*sizeof(ushort_t), stream);
    hipMemsetAsync(x2nbf + (size_t)N*EMBED, 0, (size_t)(Npad - N)*EMBED*sizeof(ushort_t), stream);

    k_embed<<<N, 64, 0, stream>>>(x, feats, feat_free, ks, Ws, bias, W_free, b_free,
                                  p, xnbf, x2nbf, N);
    k_mlp1<<<256, 256, 0, stream>>>(p, feat_free, W1, H, N);
    k_motif2<<<2048, 256, 0, stream>>>(H, motif, neg_uv, b1, W2, b2, accm, N, M);
    k_sim<<<dim3(nb, nb), 256, 0, stream>>>(xnbf, x2nbf, rowsum, colsum, posv, N);
    k_final<<<1, 256, 0, stream>>>(rowsum, colsum, posv, accm, (float*)d_out, N, M);
}

// Round 4
// 419.925 us; speedup vs baseline: 2.9866x; 1.1298x over previous
//
#include <hip/hip_runtime.h>
#include <hip/hip_bf16.h>
#include <math.h>

#define EMBED 256
#define NF 3
#define DD 64
#define BM 128
#define BN 128
#define BK 32

typedef unsigned short ushort_t;
typedef __bf16 bf16x8 __attribute__((ext_vector_type(8)));
typedef float f32x4 __attribute__((ext_vector_type(4)));

__device__ __forceinline__ void gl2lds16(const ushort_t* g, ushort_t* l) {
    __builtin_amdgcn_global_load_lds(
        (const __attribute__((address_space(1))) unsigned int*)g,
        (__attribute__((address_space(3))) unsigned int*)l, 16, 0, 0);
}

__device__ __forceinline__ ushort_t f2bf(float f) {
    __hip_bfloat16 h = __float2bfloat16(f);
    return *(ushort_t*)&h;
}
__device__ __forceinline__ float bfhi(unsigned int d) {   // high bf16 of dword
    return __builtin_bit_cast(float, d & 0xffff0000u);
}
__device__ __forceinline__ float bflo(unsigned int d) {   // low bf16 of dword
    return __builtin_bit_cast(float, d << 16);
}

// ---------------- Kernel 1: normalize + random_mapping -> bf16-normalized xn/x2n, p ----
__global__ __launch_bounds__(64) void k_embed(
    const float* __restrict__ x,
    const float* __restrict__ feats,
    const float* __restrict__ feat_free,
    const float* __restrict__ ks,
    const float* __restrict__ Ws,
    const float* __restrict__ bias,
    const float* __restrict__ W_free,
    const float* __restrict__ b_free,
    float* __restrict__ p_out,        // [3][N][32]
    ushort_t* __restrict__ xnbf,      // [Npad][256] bf16, row-normalized x
    ushort_t* __restrict__ x2nbf,     // [Npad][256] bf16, row-normalized x2
    int N)
{
    int n = blockIdx.x;
    int t = threadIdx.x;
    __shared__ float xi[NF][32];
    __shared__ float ff[32];
    __shared__ float num_s[NF];
    __shared__ float red[64];

    for (int i = 0; i < NF; ++i) {
        float v = 0.f;
        if (t < 32) v = feats[((size_t)i*N + n)*32 + t];
        red[t] = v*v;
        __syncthreads();
        if (t == 0) { float s = 0.f; for (int c = 0; c < 32; ++c) s += red[c]; red[0] = s; }
        __syncthreads();
        float sumv2 = red[0];
        float k = ks[i];
        float xn = sqrtf(sumv2);
        float scale = 0.45f / (xn * sqrtf(fabsf(k)));   // (0.9*0.5)/(|x| sqrt|k|)
        if (t < 32) {
            float xv = v * scale;
            xi[i][t] = xv;
            p_out[((size_t)i*N + n)*32 + t] = xv;
        }
        if (t == 0) num_s[i] = 1.0f + k * (scale*scale*sumv2);
        __syncthreads();
    }
    if (t < 32) ff[t] = feat_free[(size_t)n*32 + t];
    __syncthreads();

    float z[4];
    float zsq = 0.f;
    for (int i = 0; i < NF; ++i) {
        float div = 0.f;
        const float* wrow = Ws + ((size_t)i*DD + t)*32;
        #pragma unroll
        for (int c = 0; c < 32; ++c) { float d = xi[i][c] - wrow[c]; div += d*d; }
        float dist = logf(num_s[i] / (div + 1e-5f));
        float zz = expf(15.5f * dist) * cosf(dist + bias[i*DD + t]);
        z[i] = zz;
        zsq += zz*zz;
    }
    {
        float dot = 0.f;
        const float* wrow = W_free + (size_t)t*32;
        #pragma unroll
        for (int c = 0; c < 32; ++c) dot = fmaf(ff[c], wrow[c], dot);
        float zz = expf(15.5f * dot) * cosf(dot + b_free[t]);
        z[3] = zz;
        zsq += zz*zz;
    }
    red[t] = zsq; __syncthreads();
    for (int s2 = 32; s2 > 0; s2 >>= 1) { if (t < s2) red[t] += red[t+s2]; __syncthreads(); }
    float iv2 = 1.0f / sqrtf(red[0]);
    __syncthreads();

    #pragma unroll
    for (int i = 0; i < NF; ++i) x2nbf[(size_t)n*EMBED + i*DD + t] = f2bf(z[i]*iv2);
    x2nbf[(size_t)n*EMBED + 192 + t] = f2bf(z[3]*iv2);

    float xv[4];
    float s1 = 0.f;
    #pragma unroll
    for (int q = 0; q < 4; ++q) { xv[q] = x[(size_t)n*EMBED + q*64 + t]; s1 += xv[q]*xv[q]; }
    red[t] = s1; __syncthreads();
    for (int s2 = 32; s2 > 0; s2 >>= 1) { if (t < s2) red[t] += red[t+s2]; __syncthreads(); }
    float iv1 = 1.0f / sqrtf(red[0]);
    #pragma unroll
    for (int q = 0; q < 4; ++q) xnbf[(size_t)n*EMBED + q*64 + t] = f2bf(xv[q]*iv1);
}

// ---------------- Kernel 2: per-node MLP hidden partials (b1 folded in slot 2) ----
__global__ __launch_bounds__(256) void k_mlp1(
    const float* __restrict__ p,          // [3][N][32]
    const float* __restrict__ feat_free,  // [N][32]
    const float* __restrict__ W1,         // [96][64]
    const float* __restrict__ b1,         // [64]
    ushort_t* __restrict__ H,             // [4][3][N][64]
    int N)
{
    int lane = threadIdx.x & 63;
    int gw = (blockIdx.x * blockDim.x + threadIdx.x) >> 6;
    int nwaves = (gridDim.x * blockDim.x) >> 6;

    float wcol[96];
    #pragma unroll
    for (int c = 0; c < 96; ++c) wcol[c] = W1[c*64 + lane];
    float b1l = b1[lane];

    int total = 4 * N;
    for (int unit = gw; unit < total; unit += nwaves) {
        int node = __builtin_amdgcn_readfirstlane(unit >> 2);
        int prod = __builtin_amdgcn_readfirstlane(unit & 3);
        const float* P = (prod < 3) ? (p + ((size_t)prod*N + node)*32)
                                    : (feat_free + (size_t)node*32);
        float fc[32];
        #pragma unroll
        for (int c = 0; c < 32; ++c) fc[c] = P[c];
        #pragma unroll
        for (int s = 0; s < 3; ++s) {
            float h = (s == 2) ? b1l : 0.f;
            #pragma unroll
            for (int c = 0; c < 32; ++c) h = fmaf(fc[c], wcol[s*32 + c], h);
            H[(((size_t)prod*3 + s)*N + node)*64 + lane] = f2bf(h);
        }
    }
}

// ---------------- Kernel 3: motif loss, 8 lanes/row × 8 rows/wave -----------
__global__ __launch_bounds__(256) void k_motif3(
    const ushort_t* __restrict__ H,       // [4][3][N][64]
    const int* __restrict__ motif,        // [3][M]
    const int* __restrict__ neg_uv,       // [2][M]
    const float* __restrict__ W2,
    const float* __restrict__ b2,
    float* __restrict__ acc_out, int N, int M)
{
    int lane = threadIdx.x & 63;
    int sub  = lane >> 3;          // row-in-group 0..7
    int ch   = (lane & 7) * 8;     // hidden chunk base
    int gw = (blockIdx.x * blockDim.x + threadIdx.x) >> 6;
    int caseId = gw >> 10;         // 8192 waves: 1024 per case
    int rank   = gw & 1023;
    int prod  = caseId >> 1;
    int isneg = caseId & 1;
    const ushort_t* Hu = H + ((size_t)prod*3 + 0)*N*64;
    const ushort_t* Hv = H + ((size_t)prod*3 + 1)*N*64;
    const ushort_t* Hw = H + ((size_t)prod*3 + 2)*N*64;
    const int* iu = isneg ? neg_uv       : motif;
    const int* iv = isneg ? (neg_uv + M) : (motif + M);
    const int* iw = motif + 2*M;

    float w2c[8];
    #pragma unroll
    for (int c = 0; c < 8; ++c) w2c[c] = W2[ch + c];
    float b2v = b2[0];

    float accl = 0.f;
    #pragma unroll 2
    for (int r0 = rank*8; r0 < M; r0 += 8192) {
        int r = r0 + sub;
        bool ok = (r < M);
        int rc = ok ? r : 0;
        int u = iu[rc], v = iv[rc], w = iw[rc];
        uint4 du = *(const uint4*)&Hu[(size_t)u*64 + ch];
        uint4 dv = *(const uint4*)&Hv[(size_t)v*64 + ch];
        uint4 dw = *(const uint4*)&Hw[(size_t)w*64 + ch];
        float pl = 0.f;
        {
            float a, b;
            a = bflo(du.x) + bflo(dv.x) + bflo(dw.x);  b = bfhi(du.x) + bfhi(dv.x) + bfhi(dw.x);
            pl = fmaf(fmaxf(a,0.f), w2c[0], pl);       pl = fmaf(fmaxf(b,0.f), w2c[1], pl);
            a = bflo(du.y) + bflo(dv.y) + bflo(dw.y);  b = bfhi(du.y) + bfhi(dv.y) + bfhi(dw.y);
            pl = fmaf(fmaxf(a,0.f), w2c[2], pl);       pl = fmaf(fmaxf(b,0.f), w2c[3], pl);
            a = bflo(du.z) + bflo(dv.z) + bflo(dw.z);  b = bfhi(du.z) + bfhi(dv.z) + bfhi(dw.z);
            pl = fmaf(fmaxf(a,0.f), w2c[4], pl);       pl = fmaf(fmaxf(b,0.f), w2c[5], pl);
            a = bflo(du.w) + bflo(dv.w) + bflo(dw.w);  b = bfhi(du.w) + bfhi(dv.w) + bfhi(dw.w);
            pl = fmaf(fmaxf(a,0.f), w2c[6], pl);       pl = fmaf(fmaxf(b,0.f), w2c[7], pl);
        }
        // reduce within 8-lane group
        pl += __shfl_xor(pl, 1, 64);
        pl += __shfl_xor(pl, 2, 64);
        pl += __shfl_xor(pl, 4, 64);
        float logit = pl + b2v;
        float z = isneg ? -logit : logit;
        // -log_sigmoid(z) = softplus(-z)
        float sp = fmaxf(-z, 0.f) + log1pf(expf(-fabsf(z)));
        accl -= ok ? sp : 0.f;
    }
    // each row counted 8x (all lanes in its group hold sp) -> scale by 1/8
    #pragma unroll
    for (int m = 1; m < 64; m <<= 1) accl += __shfl_xor(accl, m, 64);
    if (lane == 0) atomicAdd(acc_out, accl * 0.125f);
}

// ---------------- Kernel 4: bf16 MFMA GEMM, exp(5*sim), row/col sums + diag ---------
__global__ __launch_bounds__(256) void k_sim(
    const ushort_t* __restrict__ xn, const ushort_t* __restrict__ x2n,
    float* __restrict__ rowsum, float* __restrict__ colsum, float* __restrict__ pos,
    int N)
{
    __shared__ ushort_t As[BM*BK];   // [row][k] row-major, 64B rows
    __shared__ ushort_t Bs[BN*BK];
    __shared__ float rsum_s[BM];
    __shared__ float csum_s[BN];

    int tid  = threadIdx.x;
    int lane = tid & 63;
    int w    = tid >> 6;
    int wr   = w >> 1, wc = w & 1;
    int quad = lane >> 4, l15 = lane & 15;
    int row0 = blockIdx.y * BM, col0 = blockIdx.x * BN;

    if (tid < BM) { rsum_s[tid] = 0.f; csum_s[tid] = 0.f; }

    f32x4 acc[4][4];
    #pragma unroll
    for (int i = 0; i < 4; ++i)
        #pragma unroll
        for (int j = 0; j < 4; ++j) acc[i][j] = (f32x4){0.f,0.f,0.f,0.f};

    int srow = tid >> 2;          // 0..63
    int sch  = (tid & 3) * 8;     // k-element chunk (8 bf16 = 16B)
    for (int kt = 0; kt < EMBED; kt += BK) {
        #pragma unroll
        for (int it = 0; it < 2; ++it) {
            const ushort_t* ga = xn  + ((size_t)(row0 + it*64 + srow))*EMBED + kt + sch;
            gl2lds16(ga, &As[it*2048 + tid*8]);
            const ushort_t* gb = x2n + ((size_t)(col0 + it*64 + srow))*EMBED + kt + sch;
            gl2lds16(gb, &Bs[it*2048 + tid*8]);
        }
        __syncthreads();
        bf16x8 a[4], b[4];
        #pragma unroll
        for (int ti = 0; ti < 4; ++ti)
            a[ti] = *(const bf16x8*)&As[(wr*64 + ti*16 + l15)*BK + quad*8];
        #pragma unroll
        for (int tj = 0; tj < 4; ++tj)
            b[tj] = *(const bf16x8*)&Bs[(wc*64 + tj*16 + l15)*BK + quad*8];
        #pragma unroll
        for (int ti = 0; ti < 4; ++ti)
            #pragma unroll
            for (int tj = 0; tj < 4; ++tj)
                acc[ti][tj] = __builtin_amdgcn_mfma_f32_16x16x32_bf16(a[ti], b[tj], acc[ti][tj], 0, 0, 0);
        __syncthreads();
    }

    // epilogue: e = exp(5*sim) (operands pre-normalized), diag, row/col partials
    #pragma unroll
    for (int ti = 0; ti < 4; ++ti) {
        #pragma unroll
        for (int tj = 0; tj < 4; ++tj) {
            #pragma unroll
            for (int r = 0; r < 4; ++r) {
                int gi = row0 + wr*64 + ti*16 + quad*4 + r;
                int gj = col0 + wc*64 + tj*16 + l15;
                float e = 0.f;
                if (gi < N && gj < N) {
                    e = __expf(acc[ti][tj][r] * 5.0f);
                    if (gi == gj) pos[gi] = e;
                }
                acc[ti][tj][r] = e;
            }
        }
    }
    #pragma unroll
    for (int ti = 0; ti < 4; ++ti) {
        #pragma unroll
        for (int r = 0; r < 4; ++r) {
            float rsv = acc[ti][0][r] + acc[ti][1][r] + acc[ti][2][r] + acc[ti][3][r];
            rsv += __shfl_xor(rsv, 1, 64);
            rsv += __shfl_xor(rsv, 2, 64);
            rsv += __shfl_xor(rsv, 4, 64);
            rsv += __shfl_xor(rsv, 8, 64);
            if (l15 == 0) atomicAdd(&rsum_s[wr*64 + ti*16 + quad*4 + r], rsv);
        }
    }
    #pragma unroll
    for (int tj = 0; tj < 4; ++tj) {
        float csv = 0.f;
        #pragma unroll
        for (int ti = 0; ti < 4; ++ti)
            #pragma unroll
            for (int r = 0; r < 4; ++r) csv += acc[ti][tj][r];
        csv += __shfl_xor(csv, 16, 64);
        csv += __shfl_xor(csv, 32, 64);
        if (lane < 16) atomicAdd(&csum_s[wc*64 + tj*16 + lane], csv);
    }
    __syncthreads();
    if (tid < BM) {
        int gi = row0 + tid;
        if (gi < N) atomicAdd(&rowsum[gi], rsum_s[tid]);
        int gj = col0 + tid;
        if (gj < N) atomicAdd(&colsum[gj], csum_s[tid]);
    }
}

// ---------------- Kernel 5: final scalar assembly ---------------------------
__global__ __launch_bounds__(256) void k_final(
    const float* __restrict__ rowsum, const float* __restrict__ colsum,
    const float* __restrict__ pos, const float* __restrict__ acc_motif,
    float* __restrict__ out, int N, int M)
{
    __shared__ float red1[256], red2[256];
    int t = threadIdx.x;
    float l1 = 0.f, l2 = 0.f;
    for (int i = t; i < N; i += 256) {
        float pv = pos[i];
        l1 += logf((colsum[i] - pv) / pv);
        l2 += logf((rowsum[i] - pv) / pv);
    }
    red1[t] = l1; red2[t] = l2; __syncthreads();
    for (int s = 128; s > 0; s >>= 1) {
        if (t < s) { red1[t] += red1[t+s]; red2[t] += red2[t+s]; }
        __syncthreads();
    }
    if (t == 0) {
        float cl = 0.5f * (red1[0] + red2[0]) / (float)N;
        out[0] = cl - acc_motif[0] / (float)M;
    }
}

extern "C" void kernel_launch(void* const* d_in, const int* in_sizes, int n_in,
                              void* d_out, int out_size, void* d_ws, size_t ws_size,
                              hipStream_t stream)
{
    const float* x         = (const float*)d_in[0];
    const float* feats     = (const float*)d_in[1];
    const float* feat_free = (const float*)d_in[2];
    const float* ks        = (const float*)d_in[3];
    const float* Ws        = (const float*)d_in[4];
    const float* bias      = (const float*)d_in[5];
    const float* W_free    = (const float*)d_in[6];
    const float* b_free    = (const float*)d_in[7];
    const float* W1        = (const float*)d_in[8];
    const float* b1        = (const float*)d_in[9];
    const float* W2        = (const float*)d_in[10];
    const float* b2        = (const float*)d_in[11];
    const int*   motif     = (const int*)d_in[12];
    const int*   neg_uv    = (const int*)d_in[13];
    int N = in_sizes[0] / EMBED;          // 10000
    int M = in_sizes[13] / 2;             // 50000
    int nb = (N + BM - 1) / BM;           // 79
    int Npad = nb * BM;                   // 10112

    ushort_t* xnbf  = (ushort_t*)d_ws;                     // Npad*256 bf16
    ushort_t* x2nbf = xnbf + (size_t)Npad*EMBED;           // Npad*256 bf16
    ushort_t* H     = x2nbf + (size_t)Npad*EMBED;          // 12*N*64 bf16
    float* p      = (float*)(H + (size_t)12*N*64);         // 3*N*32
    float* posv   = p + (size_t)3*N*32;                    // N
    float* rowsum = posv + N;                              // N
    float* colsum = rowsum + N;                            // N
    float* accm   = colsum + N;                            // 1

    hipMemsetAsync(rowsum, 0, (size_t)(2*N + 1) * sizeof(float), stream);
    hipMemsetAsync(xnbf  + (size_t)N*EMBED, 0, (size_t)(Npad - N)*EMBED*sizeof(ushort_t), stream);
    hipMemsetAsync(x2nbf + (size_t)N*EMBED, 0, (size_t)(Npad - N)*EMBED*sizeof(ushort_t), stream);

    k_embed<<<N, 64, 0, stream>>>(x, feats, feat_free, ks, Ws, bias, W_free, b_free,
                                  p, xnbf, x2nbf, N);
    k_mlp1<<<512, 256, 0, stream>>>(p, feat_free, W1, b1, H, N);
    k_motif3<<<2048, 256, 0, stream>>>(H, motif, neg_uv, W2, b2, accm, N, M);
    k_sim<<<dim3(nb, nb), 256, 0, stream>>>(xnbf, x2nbf, rowsum, colsum, posv, N);
    k_final<<<1, 256, 0, stream>>>(rowsum, colsum, posv, accm, (float*)d_out, N, M);
}

// Round 5
// 404.815 us; speedup vs baseline: 3.0981x; 1.0373x over previous
//
#include <hip/hip_runtime.h>
#include <hip/hip_bf16.h>
#include <math.h>

#define EMBED 256
#define NF 3
#define DD 64
#define BM 128
#define BN 128
#define BK2 64

typedef unsigned short ushort_t;
typedef __bf16 bf16x8 __attribute__((ext_vector_type(8)));
typedef float f32x4 __attribute__((ext_vector_type(4)));

__device__ __forceinline__ void gl2lds16(const ushort_t* g, ushort_t* l) {
    __builtin_amdgcn_global_load_lds(
        (const __attribute__((address_space(1))) unsigned int*)g,
        (__attribute__((address_space(3))) unsigned int*)l, 16, 0, 0);
}

__device__ __forceinline__ ushort_t f2bf(float f) {
    __hip_bfloat16 h = __float2bfloat16(f);
    return *(ushort_t*)&h;
}
__device__ __forceinline__ float bfhi(unsigned int d) {
    return __builtin_bit_cast(float, d & 0xffff0000u);
}
__device__ __forceinline__ float bflo(unsigned int d) {
    return __builtin_bit_cast(float, d << 16);
}

// ---------------- Kernel 1: normalize + random_mapping (wave-shuffle version) ----
__global__ __launch_bounds__(64) void k_embed(
    const float* __restrict__ x,
    const float* __restrict__ feats,
    const float* __restrict__ feat_free,
    const float* __restrict__ ks,
    const float* __restrict__ Ws,
    const float* __restrict__ bias,
    const float* __restrict__ W_free,
    const float* __restrict__ b_free,
    float* __restrict__ p_out,        // [3][N][32]
    ushort_t* __restrict__ xnbf,      // [Npad][256] bf16, row-normalized x
    ushort_t* __restrict__ x2nbf,     // [Npad][256] bf16, row-normalized x2
    int N)
{
    int n = blockIdx.x;
    int t = threadIdx.x;               // 0..63
    __shared__ float xi[NF][32];
    __shared__ float ffs[32];

    float v[NF];
    float ffv = 0.f;
    if (t < 32) {
        #pragma unroll
        for (int i = 0; i < NF; ++i) v[i] = feats[((size_t)i*N + n)*32 + t];
        ffv = feat_free[(size_t)n*32 + t];
    } else {
        #pragma unroll
        for (int i = 0; i < NF; ++i) v[i] = 0.f;
    }

    float num[NF];
    #pragma unroll
    for (int i = 0; i < NF; ++i) {
        float s = v[i]*v[i];
        s += __shfl_xor(s, 1, 64);  s += __shfl_xor(s, 2, 64);
        s += __shfl_xor(s, 4, 64);  s += __shfl_xor(s, 8, 64);
        s += __shfl_xor(s, 16, 64);
        s = __shfl(s, 0, 64);                       // lower-32 sum -> all lanes
        float k = ks[i];
        float scale = 0.45f / (sqrtf(s) * sqrtf(fabsf(k)));
        float xv = v[i] * scale;
        if (t < 32) {
            xi[i][t] = xv;
            p_out[((size_t)i*N + n)*32 + t] = xv;
        }
        num[i] = 1.0f + k * (scale*scale*s);
    }
    if (t < 32) ffs[t] = ffv;
    __syncthreads();

    float z[4];
    float zsq = 0.f;
    #pragma unroll
    for (int i = 0; i < NF; ++i) {
        float div = 0.f;
        const float* wrow = Ws + ((size_t)i*DD + t)*32;
        #pragma unroll
        for (int c = 0; c < 32; ++c) { float d = xi[i][c] - wrow[c]; div += d*d; }
        float dist = logf(num[i] / (div + 1e-5f));
        float zz = expf(15.5f * dist) * cosf(dist + bias[i*DD + t]);
        z[i] = zz;
        zsq += zz*zz;
    }
    {
        float dot = 0.f;
        const float* wrow = W_free + (size_t)t*32;
        #pragma unroll
        for (int c = 0; c < 32; ++c) dot = fmaf(ffs[c], wrow[c], dot);
        float zz = expf(15.5f * dot) * cosf(dot + b_free[t]);
        z[3] = zz;
        zsq += zz*zz;
    }
    zsq += __shfl_xor(zsq, 1, 64);  zsq += __shfl_xor(zsq, 2, 64);
    zsq += __shfl_xor(zsq, 4, 64);  zsq += __shfl_xor(zsq, 8, 64);
    zsq += __shfl_xor(zsq, 16, 64); zsq += __shfl_xor(zsq, 32, 64);
    float iv2 = 1.0f / sqrtf(zsq);

    #pragma unroll
    for (int i = 0; i < NF; ++i) x2nbf[(size_t)n*EMBED + i*DD + t] = f2bf(z[i]*iv2);
    x2nbf[(size_t)n*EMBED + 192 + t] = f2bf(z[3]*iv2);

    float xv[4];
    float s1 = 0.f;
    #pragma unroll
    for (int q = 0; q < 4; ++q) { xv[q] = x[(size_t)n*EMBED + q*64 + t]; s1 += xv[q]*xv[q]; }
    s1 += __shfl_xor(s1, 1, 64);  s1 += __shfl_xor(s1, 2, 64);
    s1 += __shfl_xor(s1, 4, 64);  s1 += __shfl_xor(s1, 8, 64);
    s1 += __shfl_xor(s1, 16, 64); s1 += __shfl_xor(s1, 32, 64);
    float iv1 = 1.0f / sqrtf(s1);
    #pragma unroll
    for (int q = 0; q < 4; ++q) xnbf[(size_t)n*EMBED + q*64 + t] = f2bf(xv[q]*iv1);
}

// ---------------- Kernel 2: per-node MLP hidden partials (b1 folded in slot 2) ----
__global__ __launch_bounds__(256) void k_mlp1(
    const float* __restrict__ p,          // [3][N][32]
    const float* __restrict__ feat_free,  // [N][32]
    const float* __restrict__ W1,         // [96][64]
    const float* __restrict__ b1,         // [64]
    ushort_t* __restrict__ H,             // [4][3][N][64]
    int N)
{
    int lane = threadIdx.x & 63;
    int gw = (blockIdx.x * blockDim.x + threadIdx.x) >> 6;
    int nwaves = (gridDim.x * blockDim.x) >> 6;

    float wcol[96];
    #pragma unroll
    for (int c = 0; c < 96; ++c) wcol[c] = W1[c*64 + lane];
    float b1l = b1[lane];

    int total = 4 * N;
    for (int unit = gw; unit < total; unit += nwaves) {
        int node = __builtin_amdgcn_readfirstlane(unit >> 2);
        int prod = __builtin_amdgcn_readfirstlane(unit & 3);
        const float* P = (prod < 3) ? (p + ((size_t)prod*N + node)*32)
                                    : (feat_free + (size_t)node*32);
        float fc[32];
        #pragma unroll
        for (int c = 0; c < 32; ++c) fc[c] = P[c];
        #pragma unroll
        for (int s = 0; s < 3; ++s) {
            float h = (s == 2) ? b1l : 0.f;
            #pragma unroll
            for (int c = 0; c < 32; ++c) h = fmaf(fc[c], wcol[s*32 + c], h);
            H[(((size_t)prod*3 + s)*N + node)*64 + lane] = f2bf(h);
        }
    }
}

// ---------------- Kernel 3: motif loss, 8 lanes/row × 8 rows/wave -----------
__global__ __launch_bounds__(256) void k_motif3(
    const ushort_t* __restrict__ H,       // [4][3][N][64]
    const int* __restrict__ motif,        // [3][M]
    const int* __restrict__ neg_uv,       // [2][M]
    const float* __restrict__ W2,
    const float* __restrict__ b2,
    float* __restrict__ acc_out, int N, int M)
{
    int lane = threadIdx.x & 63;
    int sub  = lane >> 3;          // row-in-group 0..7
    int ch   = (lane & 7) * 8;     // hidden chunk base
    int gw = (blockIdx.x * blockDim.x + threadIdx.x) >> 6;
    int caseId = gw >> 10;         // 8192 waves: 1024 per case
    int rank   = gw & 1023;
    int prod  = caseId >> 1;
    int isneg = caseId & 1;
    const ushort_t* Hu = H + ((size_t)prod*3 + 0)*N*64;
    const ushort_t* Hv = H + ((size_t)prod*3 + 1)*N*64;
    const ushort_t* Hw = H + ((size_t)prod*3 + 2)*N*64;
    const int* iu = isneg ? neg_uv       : motif;
    const int* iv = isneg ? (neg_uv + M) : (motif + M);
    const int* iw = motif + 2*M;

    float w2c[8];
    #pragma unroll
    for (int c = 0; c < 8; ++c) w2c[c] = W2[ch + c];
    float b2v = b2[0];

    float accl = 0.f;
    #pragma unroll 2
    for (int r0 = rank*8; r0 < M; r0 += 8192) {
        int r = r0 + sub;
        bool ok = (r < M);
        int rc = ok ? r : 0;
        int u = iu[rc], v = iv[rc], w = iw[rc];
        uint4 du = *(const uint4*)&Hu[(size_t)u*64 + ch];
        uint4 dv = *(const uint4*)&Hv[(size_t)v*64 + ch];
        uint4 dw = *(const uint4*)&Hw[(size_t)w*64 + ch];
        float pl = 0.f;
        {
            float a, b;
            a = bflo(du.x) + bflo(dv.x) + bflo(dw.x);  b = bfhi(du.x) + bfhi(dv.x) + bfhi(dw.x);
            pl = fmaf(fmaxf(a,0.f), w2c[0], pl);       pl = fmaf(fmaxf(b,0.f), w2c[1], pl);
            a = bflo(du.y) + bflo(dv.y) + bflo(dw.y);  b = bfhi(du.y) + bfhi(dv.y) + bfhi(dw.y);
            pl = fmaf(fmaxf(a,0.f), w2c[2], pl);       pl = fmaf(fmaxf(b,0.f), w2c[3], pl);
            a = bflo(du.z) + bflo(dv.z) + bflo(dw.z);  b = bfhi(du.z) + bfhi(dv.z) + bfhi(dw.z);
            pl = fmaf(fmaxf(a,0.f), w2c[4], pl);       pl = fmaf(fmaxf(b,0.f), w2c[5], pl);
            a = bflo(du.w) + bflo(dv.w) + bflo(dw.w);  b = bfhi(du.w) + bfhi(dv.w) + bfhi(dw.w);
            pl = fmaf(fmaxf(a,0.f), w2c[6], pl);       pl = fmaf(fmaxf(b,0.f), w2c[7], pl);
        }
        pl += __shfl_xor(pl, 1, 64);
        pl += __shfl_xor(pl, 2, 64);
        pl += __shfl_xor(pl, 4, 64);
        float logit = pl + b2v;
        float z = isneg ? -logit : logit;
        float sp = fmaxf(-z, 0.f) + log1pf(expf(-fabsf(z)));
        accl -= ok ? sp : 0.f;
    }
    #pragma unroll
    for (int m = 1; m < 64; m <<= 1) accl += __shfl_xor(accl, m, 64);
    if (lane == 0) atomicAdd(acc_out, accl * 0.125f);
}

// ---------------- Kernel 4: bf16 MFMA GEMM (BK=64, XOR-swizzled LDS, grouped grid) ----
__global__ __launch_bounds__(256) void k_sim(
    const ushort_t* __restrict__ xn, const ushort_t* __restrict__ x2n,
    float* __restrict__ rowsum, float* __restrict__ colsum, float* __restrict__ pos,
    int N, int nb)
{
    __shared__ ushort_t As[BM*BK2];   // [row][chunk^(row&7)] — 16B-chunk XOR swizzle
    __shared__ ushort_t Bs[BN*BK2];
    __shared__ float rsum_s[BM];
    __shared__ float csum_s[BN];

    int tid  = threadIdx.x;
    int lane = tid & 63;
    int w    = tid >> 6;
    int wr   = w >> 1, wc = w & 1;
    int quad = lane >> 4, l15 = lane & 15;

    // grouped supertile: 8 row-panels per group, sweep cols (L2 reuse)
    int pid = blockIdx.x;
    int per_group = 8 * nb;
    int group = pid / per_group;
    int rem = pid - group * per_group;
    int rowspan = min(8, nb - group * 8);
    int prow = group * 8 + rem % rowspan;
    int pcol = rem / rowspan;
    int row0 = prow * BM, col0 = pcol * BN;

    if (tid < BM) { rsum_s[tid] = 0.f; csum_s[tid] = 0.f; }

    f32x4 acc[4][4];
    #pragma unroll
    for (int i = 0; i < 4; ++i)
        #pragma unroll
        for (int j = 0; j < 4; ++j) acc[i][j] = (f32x4){0.f,0.f,0.f,0.f};

    int lrow = lane >> 3;        // 0..7 (row within wave's 8-row stripe)
    int lch  = lane & 7;         // LDS 16B-chunk slot
    for (int kt = 0; kt < EMBED; kt += BK2) {
        #pragma unroll
        for (int it = 0; it < 4; ++it) {
            int r  = w*8 + it*32 + lrow;
            int sc = lch ^ (r & 7);      // fetch swizzled source chunk
            gl2lds16(xn  + (size_t)(row0 + r)*EMBED + kt + sc*8,
                     &As[(w*8 + it*32)*BK2 + lane*8]);
            gl2lds16(x2n + (size_t)(col0 + r)*EMBED + kt + sc*8,
                     &Bs[(w*8 + it*32)*BK2 + lane*8]);
        }
        __syncthreads();
        #pragma unroll
        for (int kk = 0; kk < 2; ++kk) {
            bf16x8 a[4], b[4];
            #pragma unroll
            for (int ti = 0; ti < 4; ++ti) {
                int ra = wr*64 + ti*16 + l15;
                a[ti] = *(const bf16x8*)&As[ra*BK2 + ((kk*4 + quad) ^ (ra & 7))*8];
            }
            #pragma unroll
            for (int tj = 0; tj < 4; ++tj) {
                int rb = wc*64 + tj*16 + l15;
                b[tj] = *(const bf16x8*)&Bs[rb*BK2 + ((kk*4 + quad) ^ (rb & 7))*8];
            }
            #pragma unroll
            for (int ti = 0; ti < 4; ++ti)
                #pragma unroll
                for (int tj = 0; tj < 4; ++tj)
                    acc[ti][tj] = __builtin_amdgcn_mfma_f32_16x16x32_bf16(a[ti], b[tj], acc[ti][tj], 0, 0, 0);
        }
        __syncthreads();
    }

    // epilogue: e = exp(5*sim), diag, row/col partials
    #pragma unroll
    for (int ti = 0; ti < 4; ++ti) {
        #pragma unroll
        for (int tj = 0; tj < 4; ++tj) {
            #pragma unroll
            for (int r = 0; r < 4; ++r) {
                int gi = row0 + wr*64 + ti*16 + quad*4 + r;
                int gj = col0 + wc*64 + tj*16 + l15;
                float e = 0.f;
                if (gi < N && gj < N) {
                    e = __expf(acc[ti][tj][r] * 5.0f);
                    if (gi == gj) pos[gi] = e;
                }
                acc[ti][tj][r] = e;
            }
        }
    }
    #pragma unroll
    for (int ti = 0; ti < 4; ++ti) {
        #pragma unroll
        for (int r = 0; r < 4; ++r) {
            float rsv = acc[ti][0][r] + acc[ti][1][r] + acc[ti][2][r] + acc[ti][3][r];
            rsv += __shfl_xor(rsv, 1, 64);
            rsv += __shfl_xor(rsv, 2, 64);
            rsv += __shfl_xor(rsv, 4, 64);
            rsv += __shfl_xor(rsv, 8, 64);
            if (l15 == 0) atomicAdd(&rsum_s[wr*64 + ti*16 + quad*4 + r], rsv);
        }
    }
    #pragma unroll
    for (int tj = 0; tj < 4; ++tj) {
        float csv = 0.f;
        #pragma unroll
        for (int ti = 0; ti < 4; ++ti)
            #pragma unroll
            for (int r = 0; r < 4; ++r) csv += acc[ti][tj][r];
        csv += __shfl_xor(csv, 16, 64);
        csv += __shfl_xor(csv, 32, 64);
        if (lane < 16) atomicAdd(&csum_s[wc*64 + tj*16 + lane], csv);
    }
    __syncthreads();
    if (tid < BM) {
        int gi = row0 + tid;
        if (gi < N) atomicAdd(&rowsum[gi], rsum_s[tid]);
        int gj = col0 + tid;
        if (gj < N) atomicAdd(&colsum[gj], csum_s[tid]);
    }
}

// ---------------- Kernel 5: final scalar assembly ---------------------------
__global__ __launch_bounds__(256) void k_final(
    const float* __restrict__ rowsum, const float* __restrict__ colsum,
    const float* __restrict__ pos, const float* __restrict__ acc_motif,
    float* __restrict__ out, int N, int M)
{
    __shared__ float red1[256], red2[256];
    int t = threadIdx.x;
    float l1 = 0.f, l2 = 0.f;
    for (int i = t; i < N; i += 256) {
        float pv = pos[i];
        l1 += logf((colsum[i] - pv) / pv);
        l2 += logf((rowsum[i] - pv) / pv);
    }
    red1[t] = l1; red2[t] = l2; __syncthreads();
    for (int s = 128; s > 0; s >>= 1) {
        if (t < s) { red1[t] += red1[t+s]; red2[t] += red2[t+s]; }
        __syncthreads();
    }
    if (t == 0) {
        float cl = 0.5f * (red1[0] + red2[0]) / (float)N;
        out[0] = cl - acc_motif[0] / (float)M;
    }
}

extern "C" void kernel_launch(void* const* d_in, const int* in_sizes, int n_in,
                              void* d_out, int out_size, void* d_ws, size_t ws_size,
                              hipStream_t stream)
{
    const float* x         = (const float*)d_in[0];
    const float* feats     = (const float*)d_in[1];
    const float* feat_free = (const float*)d_in[2];
    const float* ks        = (const float*)d_in[3];
    const float* Ws        = (const float*)d_in[4];
    const float* bias      = (const float*)d_in[5];
    const float* W_free    = (const float*)d_in[6];
    const float* b_free    = (const float*)d_in[7];
    const float* W1        = (const float*)d_in[8];
    const float* b1        = (const float*)d_in[9];
    const float* W2        = (const float*)d_in[10];
    const float* b2        = (const float*)d_in[11];
    const int*   motif     = (const int*)d_in[12];
    const int*   neg_uv    = (const int*)d_in[13];
    int N = in_sizes[0] / EMBED;          // 10000
    int M = in_sizes[13] / 2;             // 50000
    int nb = (N + BM - 1) / BM;           // 79
    int Npad = nb * BM;                   // 10112

    ushort_t* xnbf  = (ushort_t*)d_ws;                     // Npad*256 bf16
    ushort_t* x2nbf = xnbf + (size_t)Npad*EMBED;           // Npad*256 bf16
    ushort_t* H     = x2nbf + (size_t)Npad*EMBED;          // 12*N*64 bf16
    float* p      = (float*)(H + (size_t)12*N*64);         // 3*N*32
    float* posv   = p + (size_t)3*N*32;                    // N
    float* rowsum = posv + N;                              // N
    float* colsum = rowsum + N;                            // N
    float* accm   = colsum + N;                            // 1

    hipMemsetAsync(rowsum, 0, (size_t)(2*N + 1) * sizeof(float), stream);
    hipMemsetAsync(xnbf  + (size_t)N*EMBED, 0, (size_t)(Npad - N)*EMBED*sizeof(ushort_t), stream);
    hipMemsetAsync(x2nbf + (size_t)N*EMBED, 0, (size_t)(Npad - N)*EMBED*sizeof(ushort_t), stream);

    k_embed<<<N, 64, 0, stream>>>(x, feats, feat_free, ks, Ws, bias, W_free, b_free,
                                  p, xnbf, x2nbf, N);
    k_mlp1<<<512, 256, 0, stream>>>(p, feat_free, W1, b1, H, N);
    k_motif3<<<2048, 256, 0, stream>>>(H, motif, neg_uv, W2, b2, accm, N, M);
    k_sim<<<nb*nb, 256, 0, stream>>>(xnbf, x2nbf, rowsum, colsum, posv, N, nb);
    k_final<<<1, 256, 0, stream>>>(rowsum, colsum, posv, accm, (float*)d_out, N, M);
}